// Round 1
// baseline (1435.530 us; speedup 1.0000x reference)
//
#include <hip/hip_runtime.h>
#include <hip/hip_bf16.h>

#define NN 50000
#define EE 800000
#define ET (NN + EE)   // edges incl. self-loops = 850000

// ---------------- CSR build ----------------

__global__ void k_init_cnt(int* __restrict__ cnt) {
    int i = blockIdx.x * blockDim.x + threadIdx.x;
    if (i < NN) cnt[i] = 1;   // self-loop pre-counted
}

__global__ void k_hist(const int* __restrict__ dst, int* __restrict__ cnt) {
    int i = blockIdx.x * blockDim.x + threadIdx.x;
    if (i < EE) atomicAdd(&cnt[dst[i]], 1);
}

// single-block inclusive scan -> rowptr (exclusive): rowptr[0]=0, rowptr[i+1]=incl_scan(cnt)[i]
__global__ __launch_bounds__(1024) void k_scan(const int* __restrict__ cnt, int* __restrict__ rowptr) {
    __shared__ int wsum[16];
    __shared__ int carry_sh;
    int t = threadIdx.x;
    int lane = t & 63, wid = t >> 6;
    if (t == 0) { carry_sh = 0; rowptr[0] = 0; }
    __syncthreads();
    for (int base = 0; base < NN; base += 1024) {
        int i = base + t;
        int v = (i < NN) ? cnt[i] : 0;
        int s = v;
        #pragma unroll
        for (int off = 1; off < 64; off <<= 1) {
            int u = __shfl_up(s, off);
            if (lane >= off) s += u;
        }
        if (lane == 63) wsum[wid] = s;
        __syncthreads();
        if (wid == 0 && lane < 16) {
            int w = wsum[lane];
            #pragma unroll
            for (int off = 1; off < 16; off <<= 1) {
                int u = __shfl_up(w, off);
                if (lane >= off) w += u;
            }
            wsum[lane] = w;
        }
        __syncthreads();
        int offset = carry_sh + (wid ? wsum[wid - 1] : 0);
        int incl = offset + s;
        if (i < NN) rowptr[i + 1] = incl;
        __syncthreads();
        if (t == 1023) carry_sh = incl;
        __syncthreads();
    }
}

__global__ void k_prep(const int* __restrict__ rowptr, int* __restrict__ writeptr, int* __restrict__ csr) {
    int i = blockIdx.x * blockDim.x + threadIdx.x;
    if (i < NN) {
        int r = rowptr[i];
        csr[r] = i;            // self-loop first
        writeptr[i] = r + 1;
    }
}

__global__ void k_scatter(const int* __restrict__ src, const int* __restrict__ dst,
                          int* __restrict__ writeptr, int* __restrict__ csr) {
    int i = blockIdx.x * blockDim.x + threadIdx.x;
    if (i < EE) {
        int pos = atomicAdd(&writeptr[dst[i]], 1);
        csr[pos] = src[i];
    }
}

// ---------------- Layer 1 ----------------

// xt1[n][t] = sum_k x[n][k]*W1[t][k]; a_src1[n][h], a_dst1[n][h]
__global__ __launch_bounds__(256) void k_l1_transform(
    const float* __restrict__ x, const float* __restrict__ W1,
    const float* __restrict__ att_src, const float* __restrict__ att_dst,
    float* __restrict__ xt1, float* __restrict__ as1, float* __restrict__ ad1)
{
    int n = blockIdx.x;
    int t = threadIdx.x;
    __shared__ __align__(16) float xs[128];
    if (t < 128) xs[t] = x[n * 128 + t];
    __syncthreads();
    const float4* w4 = (const float4*)(W1 + t * 128);
    const float4* x4 = (const float4*)xs;
    float acc = 0.f;
    #pragma unroll
    for (int k = 0; k < 32; k++) {
        float4 a = x4[k], b = w4[k];
        acc += a.x * b.x + a.y * b.y + a.z * b.z + a.w * b.w;
    }
    xt1[n * 256 + t] = acc;
    // head h = t>>6, lane c = t&63; att index == t
    float vs = acc * att_src[t];
    float vd = acc * att_dst[t];
    #pragma unroll
    for (int off = 32; off; off >>= 1) {
        vs += __shfl_down(vs, off);
        vd += __shfl_down(vd, off);
    }
    if ((t & 63) == 0) {
        int h = t >> 6;
        as1[n * 4 + h] = vs;
        ad1[n * 4 + h] = vd;
    }
}

__device__ __forceinline__ float lrelu(float e) { return e > 0.f ? e : 0.2f * e; }

// per-dst softmax + aggregate; block = dst node, 256 threads = out channels
__global__ __launch_bounds__(256) void k_l1_aggregate(
    const float* __restrict__ xt1, const float* __restrict__ as1, const float* __restrict__ ad1,
    const int* __restrict__ rowptr, const int* __restrict__ csr,
    const float* __restrict__ b1, float* __restrict__ h1)
{
    int n = blockIdx.x;
    int t = threadIdx.x;
    int lane = t & 63, wid = t >> 6;
    int beg = rowptr[n], deg = rowptr[n + 1] - beg;

    __shared__ float adsh[4];
    __shared__ float ssum[4];
    __shared__ float wpart[4][4];
    __shared__ __align__(16) float alpha_sh[256 * 4];
    __shared__ int src_sh[256];

    if (t < 4) adsh[t] = ad1[n * 4 + t];
    __syncthreads();
    float a0 = adsh[0], a1 = adsh[1], a2 = adsh[2], a3 = adsh[3];

    // pass 1: sum of exp per head
    float s0 = 0.f, s1 = 0.f, s2 = 0.f, s3 = 0.f;
    for (int j = t; j < deg; j += 256) {
        int s = csr[beg + j];
        float4 a = *(const float4*)(as1 + s * 4);
        s0 += __expf(lrelu(a.x + a0));
        s1 += __expf(lrelu(a.y + a1));
        s2 += __expf(lrelu(a.z + a2));
        s3 += __expf(lrelu(a.w + a3));
    }
    #pragma unroll
    for (int off = 32; off; off >>= 1) {
        s0 += __shfl_down(s0, off);
        s1 += __shfl_down(s1, off);
        s2 += __shfl_down(s2, off);
        s3 += __shfl_down(s3, off);
    }
    if (lane == 0) {
        wpart[wid][0] = s0; wpart[wid][1] = s1; wpart[wid][2] = s2; wpart[wid][3] = s3;
    }
    __syncthreads();
    if (t < 4) {
        float acc = wpart[0][t] + wpart[1][t] + wpart[2][t] + wpart[3][t];
        ssum[t] = acc + 1e-16f;
    }
    __syncthreads();
    float d0 = ssum[0], d1 = ssum[1], d2 = ssum[2], d3 = ssum[3];

    // pass 2: chunked alpha + gather-accumulate
    int h = wid;  // head for this thread's channel
    float acc = 0.f;
    for (int cbeg = 0; cbeg < deg; cbeg += 256) {
        int clen = min(256, deg - cbeg);
        __syncthreads();
        if (t < clen) {
            int s = csr[beg + cbeg + t];
            src_sh[t] = s;
            float4 a = *(const float4*)(as1 + s * 4);
            alpha_sh[t * 4 + 0] = __expf(lrelu(a.x + a0)) / d0;
            alpha_sh[t * 4 + 1] = __expf(lrelu(a.y + a1)) / d1;
            alpha_sh[t * 4 + 2] = __expf(lrelu(a.z + a2)) / d2;
            alpha_sh[t * 4 + 3] = __expf(lrelu(a.w + a3)) / d3;
        }
        __syncthreads();
        for (int jj = 0; jj < clen; jj++) {
            acc += xt1[src_sh[jj] * 256 + t] * alpha_sh[jj * 4 + h];
        }
    }
    float o = acc + b1[t];
    h1[n * 256 + t] = o > 0.f ? o : 0.f;
}

// ---------------- Layer 2 ----------------

__global__ __launch_bounds__(64) void k_l2_transform(
    const float* __restrict__ h1, const float* __restrict__ W2,
    const float* __restrict__ att_src, const float* __restrict__ att_dst,
    float* __restrict__ xt2, float* __restrict__ as2, float* __restrict__ ad2)
{
    int n = blockIdx.x;
    int t = threadIdx.x;  // 0..63
    __shared__ __align__(16) float hs[256];
    #pragma unroll
    for (int i = t; i < 256; i += 64) hs[i] = h1[n * 256 + i];
    __syncthreads();
    const float4* w4 = (const float4*)(W2 + t * 256);
    const float4* x4 = (const float4*)hs;
    float acc = 0.f;
    #pragma unroll
    for (int k = 0; k < 64; k++) {
        float4 a = x4[k], b = w4[k];
        acc += a.x * b.x + a.y * b.y + a.z * b.z + a.w * b.w;
    }
    xt2[n * 64 + t] = acc;
    float vs = acc * att_src[t];
    float vd = acc * att_dst[t];
    #pragma unroll
    for (int off = 32; off; off >>= 1) {
        vs += __shfl_down(vs, off);
        vd += __shfl_down(vd, off);
    }
    if (t == 0) { as2[n] = vs; ad2[n] = vd; }
}

__global__ __launch_bounds__(64) void k_l2_aggregate(
    const float* __restrict__ xt2, const float* __restrict__ as2, const float* __restrict__ ad2,
    const int* __restrict__ rowptr, const int* __restrict__ csr,
    const float* __restrict__ b2, const float* __restrict__ fcw, const float* __restrict__ fcb,
    float* __restrict__ out)
{
    int n = blockIdx.x;
    int t = threadIdx.x;  // 0..63
    int beg = rowptr[n], deg = rowptr[n + 1] - beg;
    float adv = ad2[n];

    float lsum = 0.f;
    for (int j = t; j < deg; j += 64) {
        int s = csr[beg + j];
        lsum += __expf(lrelu(as2[s] + adv));
    }
    #pragma unroll
    for (int off = 32; off; off >>= 1) lsum += __shfl_xor(lsum, off);
    float denom = lsum + 1e-16f;

    __shared__ float alpha_sh[64];
    __shared__ int src_sh[64];
    float acc = 0.f;
    for (int cbeg = 0; cbeg < deg; cbeg += 64) {
        int clen = min(64, deg - cbeg);
        __syncthreads();
        if (t < clen) {
            int s = csr[beg + cbeg + t];
            src_sh[t] = s;
            alpha_sh[t] = __expf(lrelu(as2[s] + adv)) / denom;
        }
        __syncthreads();
        for (int jj = 0; jj < clen; jj++) {
            acc += xt2[src_sh[jj] * 64 + t] * alpha_sh[jj];
        }
    }
    float o = acc + b2[t];
    o = o > 0.f ? o : 0.f;
    float z = o * fcw[t];
    #pragma unroll
    for (int off = 32; off; off >>= 1) z += __shfl_xor(z, off);
    if (t == 0) out[n] = 1.f / (1.f + __expf(-(z + fcb[0])));
}

// ---------------- launch ----------------

extern "C" void kernel_launch(void* const* d_in, const int* in_sizes, int n_in,
                              void* d_out, int out_size, void* d_ws, size_t ws_size,
                              hipStream_t stream) {
    const float* x    = (const float*)d_in[0];
    const int*   ei   = (const int*)d_in[1];    // [2][E] int32
    const float* W1   = (const float*)d_in[2];
    const float* as1w = (const float*)d_in[3];
    const float* ad1w = (const float*)d_in[4];
    const float* b1   = (const float*)d_in[5];
    const float* W2   = (const float*)d_in[6];
    const float* as2w = (const float*)d_in[7];
    const float* ad2w = (const float*)d_in[8];
    const float* b2   = (const float*)d_in[9];
    const float* fcw  = (const float*)d_in[10];
    const float* fcb  = (const float*)d_in[11];
    float* out = (float*)d_out;

    const int* src = ei;
    const int* dst = ei + EE;

    char* base = (char*)d_ws;
    size_t off = 0;
    auto alloc = [&](size_t bytes) -> void* {
        void* p = base + off;
        off = (off + bytes + 255) & ~(size_t)255;
        return p;
    };
    int*   rowptr   = (int*)alloc((NN + 1) * sizeof(int));
    int*   cnt      = (int*)alloc(NN * sizeof(int));
    int*   writeptr = (int*)alloc(NN * sizeof(int));
    int*   csr      = (int*)alloc(ET * sizeof(int));
    float* xt1      = (float*)alloc((size_t)NN * 256 * sizeof(float));
    float* h1       = (float*)alloc((size_t)NN * 256 * sizeof(float));
    float* as1      = (float*)alloc(NN * 4 * sizeof(float));
    float* ad1      = (float*)alloc(NN * 4 * sizeof(float));
    float* as2      = (float*)alloc(NN * sizeof(float));
    float* ad2      = (float*)alloc(NN * sizeof(float));
    float* xt2      = xt1;  // xt1 dead after l1_aggregate; reuse for layer 2

    k_init_cnt<<<(NN + 255) / 256, 256, 0, stream>>>(cnt);
    k_hist<<<(EE + 255) / 256, 256, 0, stream>>>(dst, cnt);
    k_scan<<<1, 1024, 0, stream>>>(cnt, rowptr);
    k_prep<<<(NN + 255) / 256, 256, 0, stream>>>(rowptr, writeptr, csr);
    k_scatter<<<(EE + 255) / 256, 256, 0, stream>>>(src, dst, writeptr, csr);

    k_l1_transform<<<NN, 256, 0, stream>>>(x, W1, as1w, ad1w, xt1, as1, ad1);
    k_l1_aggregate<<<NN, 256, 0, stream>>>(xt1, as1, ad1, rowptr, csr, b1, h1);
    k_l2_transform<<<NN, 64, 0, stream>>>(h1, W2, as2w, ad2w, xt2, as2, ad2);
    k_l2_aggregate<<<NN, 64, 0, stream>>>(xt2, as2, ad2, rowptr, csr, b2, fcw, fcb, out);
}

// Round 2
// 526.635 us; speedup vs baseline: 2.7259x; 2.7259x over previous
//
#include <hip/hip_runtime.h>
#include <hip/hip_bf16.h>

#define NN 50000
#define EE 800000
#define ET (NN + EE)   // edges incl. self-loops = 850000

// ---------------- CSR build ----------------

__global__ void k_init_cnt(int* __restrict__ cnt) {
    int i = blockIdx.x * blockDim.x + threadIdx.x;
    if (i < NN) cnt[i] = 1;   // self-loop pre-counted
}

__global__ void k_hist(const int* __restrict__ dst, int* __restrict__ cnt) {
    int i = blockIdx.x * blockDim.x + threadIdx.x;
    if (i < EE) atomicAdd(&cnt[dst[i]], 1);
}

// single-block inclusive scan -> rowptr (exclusive): rowptr[0]=0, rowptr[i+1]=incl_scan(cnt)[i]
__global__ __launch_bounds__(1024) void k_scan(const int* __restrict__ cnt, int* __restrict__ rowptr) {
    __shared__ int wsum[16];
    __shared__ int carry_sh;
    int t = threadIdx.x;
    int lane = t & 63, wid = t >> 6;
    if (t == 0) { carry_sh = 0; rowptr[0] = 0; }
    __syncthreads();
    for (int base = 0; base < NN; base += 1024) {
        int i = base + t;
        int v = (i < NN) ? cnt[i] : 0;
        int s = v;
        #pragma unroll
        for (int off = 1; off < 64; off <<= 1) {
            int u = __shfl_up(s, off);
            if (lane >= off) s += u;
        }
        if (lane == 63) wsum[wid] = s;
        __syncthreads();
        if (wid == 0 && lane < 16) {
            int w = wsum[lane];
            #pragma unroll
            for (int off = 1; off < 16; off <<= 1) {
                int u = __shfl_up(w, off);
                if (lane >= off) w += u;
            }
            wsum[lane] = w;
        }
        __syncthreads();
        int offset = carry_sh + (wid ? wsum[wid - 1] : 0);
        int incl = offset + s;
        if (i < NN) rowptr[i + 1] = incl;
        __syncthreads();
        if (t == 1023) carry_sh = incl;
        __syncthreads();
    }
}

__global__ void k_prep(const int* __restrict__ rowptr, int* __restrict__ writeptr, int* __restrict__ csr) {
    int i = blockIdx.x * blockDim.x + threadIdx.x;
    if (i < NN) {
        int r = rowptr[i];
        csr[r] = i;            // self-loop first
        writeptr[i] = r + 1;
    }
}

__global__ void k_scatter(const int* __restrict__ src, const int* __restrict__ dst,
                          int* __restrict__ writeptr, int* __restrict__ csr) {
    int i = blockIdx.x * blockDim.x + threadIdx.x;
    if (i < EE) {
        int pos = atomicAdd(&writeptr[dst[i]], 1);
        csr[pos] = src[i];
    }
}

// ---------------- weight transpose (once per call, tiny) ----------------
// W[Nrows][Kcols] row-major -> Wt[Kcols][Nrows]
__global__ void k_tr(const float* __restrict__ W, float* __restrict__ Wt, int Nrows, int Kcols) {
    int i = blockIdx.x * blockDim.x + threadIdx.x;
    if (i < Nrows * Kcols) {
        int n = i / Kcols, k = i % Kcols;
        Wt[k * Nrows + n] = W[i];
    }
}

// ---------------- tiled GEMM with fused attention-score epilogue ----------------
// C[M][N] = A[M][K] @ Wt[K][N]; as_[m][h] = sum_c C[m][c]*atts[h][c-64h], same for ad_.
// Block: 256 threads, 64-row M tile, full N. Thread (tx=t&15, ty=t>>4) computes
// rows ty*4..+3, cols 4*tx + 64*j for j<QJ (quad j == head j).
template<int K, int N, int NH>
__global__ __launch_bounds__(256) void k_gemm_att(
    const float* __restrict__ A, const float* __restrict__ Wt,
    const float* __restrict__ atts, const float* __restrict__ attd,
    float* __restrict__ C, float* __restrict__ as_, float* __restrict__ ad_,
    int M)
{
    constexpr int QJ = N / 64;          // col-quads per thread (4 or 1)
    constexpr int KT = 32;
    __shared__ float xs[64][KT + 1];    // +1 pad: 16-way -> 2-way (free)
    __shared__ float ws[KT][N];         // read at 4*tx: 2-way (free)
    int t = threadIdx.x;
    int tx = t & 15, ty = t >> 4;
    int m0 = blockIdx.x * 64;

    float4 acc[4][QJ];
    #pragma unroll
    for (int i = 0; i < 4; i++)
        #pragma unroll
        for (int j = 0; j < QJ; j++) acc[i][j] = make_float4(0.f, 0.f, 0.f, 0.f);

    for (int k0 = 0; k0 < K; k0 += KT) {
        __syncthreads();
        // stage xs: 64 rows x 32 cols = 512 quads, 2 per thread, coalesced
        #pragma unroll
        for (int i = 0; i < 2; i++) {
            int idx = t + 256 * i;
            int row = idx >> 3, q = idx & 7;
            int gr = m0 + row; if (gr >= M) gr = M - 1;
            float4 v = *(const float4*)(A + (size_t)gr * K + k0 + q * 4);
            *(float4*)&xs[row][q * 4] = v;
        }
        // stage ws: KT x N floats, coalesced
        constexpr int WQ = (KT * N / 4) / 256;
        #pragma unroll
        for (int i = 0; i < WQ; i++) {
            int idx = t + 256 * i;
            int kk = idx / (N / 4), c4 = idx % (N / 4);
            float4 v = *(const float4*)(Wt + (size_t)(k0 + kk) * N + c4 * 4);
            *(float4*)&ws[kk][c4 * 4] = v;
        }
        __syncthreads();
        #pragma unroll
        for (int kk = 0; kk < KT; kk++) {
            float xv[4];
            #pragma unroll
            for (int i = 0; i < 4; i++) xv[i] = xs[ty * 4 + i][kk];
            #pragma unroll
            for (int j = 0; j < QJ; j++) {
                float4 wv = *(const float4*)&ws[kk][tx * 4 + 64 * j];
                #pragma unroll
                for (int i = 0; i < 4; i++) {
                    acc[i][j].x += xv[i] * wv.x;
                    acc[i][j].y += xv[i] * wv.y;
                    acc[i][j].z += xv[i] * wv.z;
                    acc[i][j].w += xv[i] * wv.w;
                }
            }
        }
    }

    // epilogue: store C + fused att-score reduction
    float4 a_s[QJ], a_d[QJ];
    #pragma unroll
    for (int j = 0; j < QJ; j++) {
        a_s[j] = *(const float4*)(atts + j * 64 + tx * 4);
        a_d[j] = *(const float4*)(attd + j * 64 + tx * 4);
    }
    #pragma unroll
    for (int i = 0; i < 4; i++) {
        int row = m0 + ty * 4 + i;
        bool ok = row < M;
        float ps[QJ], pd[QJ];
        #pragma unroll
        for (int j = 0; j < QJ; j++) {
            if (ok) *(float4*)(C + (size_t)row * N + tx * 4 + 64 * j) = acc[i][j];
            ps[j] = acc[i][j].x * a_s[j].x + acc[i][j].y * a_s[j].y
                  + acc[i][j].z * a_s[j].z + acc[i][j].w * a_s[j].w;
            pd[j] = acc[i][j].x * a_d[j].x + acc[i][j].y * a_d[j].y
                  + acc[i][j].z * a_d[j].z + acc[i][j].w * a_d[j].w;
        }
        #pragma unroll
        for (int off = 8; off; off >>= 1) {
            #pragma unroll
            for (int j = 0; j < QJ; j++) {
                ps[j] += __shfl_xor(ps[j], off);
                pd[j] += __shfl_xor(pd[j], off);
            }
        }
        if (tx == 0 && ok) {
            if (NH == 4) {
                *(float4*)(as_ + row * 4) = make_float4(ps[0], ps[1], ps[2], ps[3]);
                *(float4*)(ad_ + row * 4) = make_float4(pd[0], pd[1], pd[2], pd[3]);
            } else {
                as_[row] = ps[0];
                ad_[row] = pd[0];
            }
        }
    }
}

__device__ __forceinline__ float lrelu(float e) { return e > 0.f ? e : 0.2f * e; }

// ---------------- Layer-1 aggregation: single-pass, wave-per-edge ----------------
// out = (sum_j e_j * xt1[src_j]) / (sum_j e_j); block=dst node, 4 waves stride edges,
// lane holds float4 of channels 4*lane (head = lane>>4).
__global__ __launch_bounds__(256) void k_l1_agg(
    const float* __restrict__ xt1, const float* __restrict__ as1, const float* __restrict__ ad1,
    const int* __restrict__ rowptr, const int* __restrict__ csr,
    const float* __restrict__ b1, float* __restrict__ h1)
{
    int n = blockIdx.x;
    int t = threadIdx.x;
    int lane = t & 63, w = t >> 6;
    int beg = rowptr[n], deg = rowptr[n + 1] - beg;
    int h = lane >> 4;
    float adv = ad1[n * 4 + h];

    float4 acc = make_float4(0.f, 0.f, 0.f, 0.f);
    float esum = 0.f;
    for (int j = w; j < deg; j += 4) {
        int s = csr[beg + j];
        float e = __expf(lrelu(as1[s * 4 + h] + adv));
        float4 row = *(const float4*)(xt1 + (size_t)s * 256 + 4 * lane);
        esum += e;
        acc.x += row.x * e; acc.y += row.y * e; acc.z += row.z * e; acc.w += row.w * e;
    }
    __shared__ float4 accsh[4][64];
    __shared__ float esh[4][64];
    accsh[w][lane] = acc;
    esh[w][lane] = esum;
    __syncthreads();
    if (w == 0) {
        float4 a1 = accsh[1][lane], a2 = accsh[2][lane], a3 = accsh[3][lane];
        acc.x += a1.x + a2.x + a3.x;
        acc.y += a1.y + a2.y + a3.y;
        acc.z += a1.z + a2.z + a3.z;
        acc.w += a1.w + a2.w + a3.w;
        esum += esh[1][lane] + esh[2][lane] + esh[3][lane];
        float rs = 1.f / (esum + 1e-16f);
        float4 b = *(const float4*)(b1 + 4 * lane);
        float4 o;
        o.x = fmaxf(acc.x * rs + b.x, 0.f);
        o.y = fmaxf(acc.y * rs + b.y, 0.f);
        o.z = fmaxf(acc.z * rs + b.z, 0.f);
        o.w = fmaxf(acc.w * rs + b.w, 0.f);
        *(float4*)(h1 + (size_t)n * 256 + 4 * lane) = o;
    }
}

// ---------------- Layer-2 aggregation + fc + sigmoid ----------------
__global__ __launch_bounds__(256) void k_l2_agg(
    const float* __restrict__ xt2, const float* __restrict__ as2, const float* __restrict__ ad2,
    const int* __restrict__ rowptr, const int* __restrict__ csr,
    const float* __restrict__ b2, const float* __restrict__ fcw, const float* __restrict__ fcb,
    float* __restrict__ out)
{
    int n = blockIdx.x;
    int t = threadIdx.x;
    int lane = t & 63, w = t >> 6;
    int beg = rowptr[n], deg = rowptr[n + 1] - beg;
    float adv = ad2[n];

    float acc = 0.f, esum = 0.f;
    for (int j = w; j < deg; j += 4) {
        int s = csr[beg + j];
        float e = __expf(lrelu(as2[s] + adv));
        acc += xt2[(size_t)s * 64 + lane] * e;
        esum += e;
    }
    __shared__ float accsh[4][64];
    __shared__ float esh[4][64];
    accsh[w][lane] = acc;
    esh[w][lane] = esum;
    __syncthreads();
    if (w == 0) {
        acc += accsh[1][lane] + accsh[2][lane] + accsh[3][lane];
        esum += esh[1][lane] + esh[2][lane] + esh[3][lane];
        float o = acc / (esum + 1e-16f) + b2[lane];
        o = fmaxf(o, 0.f);
        float z = o * fcw[lane];
        #pragma unroll
        for (int off = 32; off; off >>= 1) z += __shfl_xor(z, off);
        if (lane == 0) out[n] = 1.f / (1.f + __expf(-(z + fcb[0])));
    }
}

// ---------------- launch ----------------

extern "C" void kernel_launch(void* const* d_in, const int* in_sizes, int n_in,
                              void* d_out, int out_size, void* d_ws, size_t ws_size,
                              hipStream_t stream) {
    const float* x    = (const float*)d_in[0];
    const int*   ei   = (const int*)d_in[1];    // [2][E]
    const float* W1   = (const float*)d_in[2];
    const float* as1w = (const float*)d_in[3];
    const float* ad1w = (const float*)d_in[4];
    const float* b1   = (const float*)d_in[5];
    const float* W2   = (const float*)d_in[6];
    const float* as2w = (const float*)d_in[7];
    const float* ad2w = (const float*)d_in[8];
    const float* b2   = (const float*)d_in[9];
    const float* fcw  = (const float*)d_in[10];
    const float* fcb  = (const float*)d_in[11];
    float* out = (float*)d_out;

    const int* src = ei;
    const int* dst = ei + EE;

    char* base = (char*)d_ws;
    size_t off = 0;
    auto alloc = [&](size_t bytes) -> void* {
        void* p = base + off;
        off = (off + bytes + 255) & ~(size_t)255;
        return p;
    };
    int*   rowptr   = (int*)alloc((NN + 1) * sizeof(int));
    int*   cnt      = (int*)alloc(NN * sizeof(int));
    int*   writeptr = (int*)alloc(NN * sizeof(int));
    int*   csr      = (int*)alloc(ET * sizeof(int));
    float* xt1      = (float*)alloc((size_t)NN * 256 * sizeof(float));
    float* h1       = (float*)alloc((size_t)NN * 256 * sizeof(float));
    float* as1      = (float*)alloc(NN * 4 * sizeof(float));
    float* ad1      = (float*)alloc(NN * 4 * sizeof(float));
    float* as2      = (float*)alloc(NN * sizeof(float));
    float* ad2      = (float*)alloc(NN * sizeof(float));
    float* Wt1      = (float*)alloc(256 * 128 * sizeof(float));
    float* Wt2      = (float*)alloc(64 * 256 * sizeof(float));
    float* xt2      = xt1;  // xt1 dead after l1_agg; reuse for layer 2

    // CSR build
    k_init_cnt<<<(NN + 255) / 256, 256, 0, stream>>>(cnt);
    k_hist<<<(EE + 255) / 256, 256, 0, stream>>>(dst, cnt);
    k_scan<<<1, 1024, 0, stream>>>(cnt, rowptr);
    k_prep<<<(NN + 255) / 256, 256, 0, stream>>>(rowptr, writeptr, csr);
    k_scatter<<<(EE + 255) / 256, 256, 0, stream>>>(src, dst, writeptr, csr);

    // weight transposes
    k_tr<<<(256 * 128 + 255) / 256, 256, 0, stream>>>(W1, Wt1, 256, 128);
    k_tr<<<(64 * 256 + 255) / 256, 256, 0, stream>>>(W2, Wt2, 64, 256);

    int gblocks = (NN + 63) / 64;  // 782
    k_gemm_att<128, 256, 4><<<gblocks, 256, 0, stream>>>(x, Wt1, as1w, ad1w, xt1, as1, ad1, NN);
    k_l1_agg<<<NN, 256, 0, stream>>>(xt1, as1, ad1, rowptr, csr, b1, h1);
    k_gemm_att<256, 64, 1><<<gblocks, 256, 0, stream>>>(h1, Wt2, as2w, ad2w, xt2, as2, ad2, NN);
    k_l2_agg<<<NN, 256, 0, stream>>>(xt2, as2, ad2, rowptr, csr, b2, fcw, fcb, out);
}

// Round 3
// 466.494 us; speedup vs baseline: 3.0773x; 1.1289x over previous
//
#include <hip/hip_runtime.h>
#include <hip/hip_bf16.h>

#define NN 50000
#define EE 800000
#define ET (NN + EE)   // edges incl. self-loops = 850000
#define SG ((NN + 255) / 256)   // scan blocks = 196

__device__ __forceinline__ float bf2f(unsigned short u) {
    union { unsigned int i; float f; } v; v.i = ((unsigned int)u) << 16; return v.f;
}
__device__ __forceinline__ unsigned short f2bf(float f) {
    __hip_bfloat16 h = __float2bfloat16(f);
    return *reinterpret_cast<unsigned short*>(&h);
}

// ---------------- CSR build ----------------

__global__ void k_init_cnt(int* __restrict__ cnt) {
    int i = blockIdx.x * blockDim.x + threadIdx.x;
    if (i < NN) cnt[i] = 1;   // self-loop pre-counted
}

__global__ void k_hist(const int* __restrict__ dst, int* __restrict__ cnt) {
    int i = blockIdx.x * blockDim.x + threadIdx.x;
    if (i < EE) atomicAdd(&cnt[dst[i]], 1);
}

// parallel 3-phase scan: per-block inclusive partials + block sums
__global__ __launch_bounds__(256) void k_scan1(const int* __restrict__ cnt,
                                               int* __restrict__ tmp, int* __restrict__ bsum) {
    int b = blockIdx.x, t = threadIdx.x, i = b * 256 + t;
    int lane = t & 63, w = t >> 6;
    int v = (i < NN) ? cnt[i] : 0;
    int s = v;
    #pragma unroll
    for (int off = 1; off < 64; off <<= 1) {
        int u = __shfl_up(s, off);
        if (lane >= off) s += u;
    }
    __shared__ int ws[4];
    if (lane == 63) ws[w] = s;
    __syncthreads();
    if (t == 0) {
        int a = 0;
        #pragma unroll
        for (int k = 0; k < 4; k++) { int x = ws[k]; ws[k] = a; a += x; }
        bsum[b] = a;
    }
    __syncthreads();
    s += ws[w];
    if (i < NN) tmp[i] = s;   // inclusive within block
}

__global__ __launch_bounds__(256) void k_scan2(const int* __restrict__ bsum, int* __restrict__ boff) {
    int t = threadIdx.x, lane = t & 63, w = t >> 6;
    int v = (t < SG) ? bsum[t] : 0;
    int s = v;
    #pragma unroll
    for (int off = 1; off < 64; off <<= 1) {
        int u = __shfl_up(s, off);
        if (lane >= off) s += u;
    }
    __shared__ int ws[4];
    if (lane == 63) ws[w] = s;
    __syncthreads();
    if (t == 0) {
        int a = 0;
        #pragma unroll
        for (int k = 0; k < 4; k++) { int x = ws[k]; ws[k] = a; a += x; }
    }
    __syncthreads();
    s += ws[w];
    if (t < SG) boff[t] = s - v;   // exclusive
}

// rowptr[i+1] = tmp[i] + boff[block]; also seed csr self-loop + writeptr
__global__ void k_scan3_prep(const int* __restrict__ tmp, const int* __restrict__ boff,
                             int* __restrict__ rowptr, int* __restrict__ writeptr,
                             int* __restrict__ csr) {
    int i = blockIdx.x * blockDim.x + threadIdx.x;
    if (i == 0) rowptr[0] = 0;
    if (i < NN) {
        int incl = tmp[i] + boff[i >> 8];
        rowptr[i + 1] = incl;
        int v = (i & 255) ? tmp[i - 1] + boff[i >> 8] : boff[i >> 8];  // exclusive = rowptr[i]
        csr[v] = i;            // self-loop first
        writeptr[i] = v + 1;
    }
}

__global__ void k_scatter(const int* __restrict__ src, const int* __restrict__ dst,
                          int* __restrict__ writeptr, int* __restrict__ csr) {
    int i = blockIdx.x * blockDim.x + threadIdx.x;
    if (i < EE) {
        int pos = atomicAdd(&writeptr[dst[i]], 1);
        csr[pos] = src[i];
    }
}

// ---------------- weight transpose (once per call, tiny) ----------------
__global__ void k_tr(const float* __restrict__ W, float* __restrict__ Wt, int Nrows, int Kcols) {
    int i = blockIdx.x * blockDim.x + threadIdx.x;
    if (i < Nrows * Kcols) {
        int n = i / Kcols, k = i % Kcols;
        Wt[k * Nrows + n] = W[i];
    }
}

// ---------------- tiled GEMM, bf16 C output, fused attention-score epilogue ----------------
template<int K, int N, int NH>
__global__ __launch_bounds__(256) void k_gemm_att(
    const float* __restrict__ A, const float* __restrict__ Wt,
    const float* __restrict__ atts, const float* __restrict__ attd,
    unsigned short* __restrict__ C, float* __restrict__ as_, float* __restrict__ ad_,
    int M)
{
    constexpr int QJ = N / 64;          // col-quads per thread (4 or 1)
    constexpr int KT = 32;
    __shared__ float xs[64][KT + 1];    // +1 pad: 2-way conflicts only (free)
    __shared__ float ws[KT][N];         // read at 4*tx: 2-way (free)
    int t = threadIdx.x;
    int tx = t & 15, ty = t >> 4;
    int m0 = blockIdx.x * 64;

    float4 acc[4][QJ];
    #pragma unroll
    for (int i = 0; i < 4; i++)
        #pragma unroll
        for (int j = 0; j < QJ; j++) acc[i][j] = make_float4(0.f, 0.f, 0.f, 0.f);

    for (int k0 = 0; k0 < K; k0 += KT) {
        __syncthreads();
        #pragma unroll
        for (int i = 0; i < 2; i++) {
            int idx = t + 256 * i;
            int row = idx >> 3, q = idx & 7;
            int gr = m0 + row; if (gr >= M) gr = M - 1;
            float4 v = *(const float4*)(A + (size_t)gr * K + k0 + q * 4);
            *(float4*)&xs[row][q * 4] = v;
        }
        constexpr int WQ = (KT * N / 4) / 256;
        #pragma unroll
        for (int i = 0; i < WQ; i++) {
            int idx = t + 256 * i;
            int kk = idx / (N / 4), c4 = idx % (N / 4);
            float4 v = *(const float4*)(Wt + (size_t)(k0 + kk) * N + c4 * 4);
            *(float4*)&ws[kk][c4 * 4] = v;
        }
        __syncthreads();
        #pragma unroll
        for (int kk = 0; kk < KT; kk++) {
            float xv[4];
            #pragma unroll
            for (int i = 0; i < 4; i++) xv[i] = xs[ty * 4 + i][kk];
            #pragma unroll
            for (int j = 0; j < QJ; j++) {
                float4 wv = *(const float4*)&ws[kk][tx * 4 + 64 * j];
                #pragma unroll
                for (int i = 0; i < 4; i++) {
                    acc[i][j].x += xv[i] * wv.x;
                    acc[i][j].y += xv[i] * wv.y;
                    acc[i][j].z += xv[i] * wv.z;
                    acc[i][j].w += xv[i] * wv.w;
                }
            }
        }
    }

    float4 a_s[QJ], a_d[QJ];
    #pragma unroll
    for (int j = 0; j < QJ; j++) {
        a_s[j] = *(const float4*)(atts + j * 64 + tx * 4);
        a_d[j] = *(const float4*)(attd + j * 64 + tx * 4);
    }
    #pragma unroll
    for (int i = 0; i < 4; i++) {
        int row = m0 + ty * 4 + i;
        bool ok = row < M;
        float ps[QJ], pd[QJ];
        #pragma unroll
        for (int j = 0; j < QJ; j++) {
            if (ok) {
                ushort4 pk;
                pk.x = f2bf(acc[i][j].x); pk.y = f2bf(acc[i][j].y);
                pk.z = f2bf(acc[i][j].z); pk.w = f2bf(acc[i][j].w);
                *(ushort4*)(C + (size_t)row * N + tx * 4 + 64 * j) = pk;
            }
            ps[j] = acc[i][j].x * a_s[j].x + acc[i][j].y * a_s[j].y
                  + acc[i][j].z * a_s[j].z + acc[i][j].w * a_s[j].w;
            pd[j] = acc[i][j].x * a_d[j].x + acc[i][j].y * a_d[j].y
                  + acc[i][j].z * a_d[j].z + acc[i][j].w * a_d[j].w;
        }
        #pragma unroll
        for (int off = 8; off; off >>= 1) {
            #pragma unroll
            for (int j = 0; j < QJ; j++) {
                ps[j] += __shfl_xor(ps[j], off);
                pd[j] += __shfl_xor(pd[j], off);
            }
        }
        if (tx == 0 && ok) {
            if (NH == 4) {
                *(float4*)(as_ + row * 4) = make_float4(ps[0], ps[1], ps[2], ps[3]);
                *(float4*)(ad_ + row * 4) = make_float4(pd[0], pd[1], pd[2], pd[3]);
            } else {
                as_[row] = ps[0];
                ad_[row] = pd[0];
            }
        }
    }
}

__device__ __forceinline__ float lrelu(float e) { return e > 0.f ? e : 0.2f * e; }

// ---------------- Layer-1 aggregation: single-pass, bf16 gather ----------------
__global__ __launch_bounds__(256) void k_l1_agg(
    const unsigned short* __restrict__ xt1, const float* __restrict__ as1, const float* __restrict__ ad1,
    const int* __restrict__ rowptr, const int* __restrict__ csr,
    const float* __restrict__ b1, float* __restrict__ h1)
{
    int n = blockIdx.x;
    int t = threadIdx.x;
    int lane = t & 63, w = t >> 6;
    int beg = rowptr[n], deg = rowptr[n + 1] - beg;
    int h = lane >> 4;
    float adv = ad1[n * 4 + h];

    float4 acc = make_float4(0.f, 0.f, 0.f, 0.f);
    float esum = 0.f;
    for (int j = w; j < deg; j += 4) {
        int s = csr[beg + j];
        float e = __expf(lrelu(as1[s * 4 + h] + adv));
        ushort4 r = *(const ushort4*)(xt1 + (size_t)s * 256 + 4 * lane);
        esum += e;
        acc.x += bf2f(r.x) * e; acc.y += bf2f(r.y) * e;
        acc.z += bf2f(r.z) * e; acc.w += bf2f(r.w) * e;
    }
    __shared__ float4 accsh[4][64];
    __shared__ float esh[4][64];
    accsh[w][lane] = acc;
    esh[w][lane] = esum;
    __syncthreads();
    if (w == 0) {
        float4 a1 = accsh[1][lane], a2 = accsh[2][lane], a3 = accsh[3][lane];
        acc.x += a1.x + a2.x + a3.x;
        acc.y += a1.y + a2.y + a3.y;
        acc.z += a1.z + a2.z + a3.z;
        acc.w += a1.w + a2.w + a3.w;
        esum += esh[1][lane] + esh[2][lane] + esh[3][lane];
        float rs = 1.f / (esum + 1e-16f);
        float4 b = *(const float4*)(b1 + 4 * lane);
        float4 o;
        o.x = fmaxf(acc.x * rs + b.x, 0.f);
        o.y = fmaxf(acc.y * rs + b.y, 0.f);
        o.z = fmaxf(acc.z * rs + b.z, 0.f);
        o.w = fmaxf(acc.w * rs + b.w, 0.f);
        *(float4*)(h1 + (size_t)n * 256 + 4 * lane) = o;
    }
}

// ---------------- Layer-2 aggregation + fc + sigmoid ----------------
__global__ __launch_bounds__(256) void k_l2_agg(
    const unsigned short* __restrict__ xt2, const float* __restrict__ as2, const float* __restrict__ ad2,
    const int* __restrict__ rowptr, const int* __restrict__ csr,
    const float* __restrict__ b2, const float* __restrict__ fcw, const float* __restrict__ fcb,
    float* __restrict__ out)
{
    int n = blockIdx.x;
    int t = threadIdx.x;
    int lane = t & 63, w = t >> 6;
    int beg = rowptr[n], deg = rowptr[n + 1] - beg;
    float adv = ad2[n];

    float acc = 0.f, esum = 0.f;
    for (int j = w; j < deg; j += 4) {
        int s = csr[beg + j];
        float e = __expf(lrelu(as2[s] + adv));
        acc += bf2f(xt2[(size_t)s * 64 + lane]) * e;
        esum += e;
    }
    __shared__ float accsh[4][64];
    __shared__ float esh[4][64];
    accsh[w][lane] = acc;
    esh[w][lane] = esum;
    __syncthreads();
    if (w == 0) {
        acc += accsh[1][lane] + accsh[2][lane] + accsh[3][lane];
        esum += esh[1][lane] + esh[2][lane] + esh[3][lane];
        float o = acc / (esum + 1e-16f) + b2[lane];
        o = fmaxf(o, 0.f);
        float z = o * fcw[lane];
        #pragma unroll
        for (int off = 32; off; off >>= 1) z += __shfl_xor(z, off);
        if (lane == 0) out[n] = 1.f / (1.f + __expf(-(z + fcb[0])));
    }
}

// ---------------- launch ----------------

extern "C" void kernel_launch(void* const* d_in, const int* in_sizes, int n_in,
                              void* d_out, int out_size, void* d_ws, size_t ws_size,
                              hipStream_t stream) {
    const float* x    = (const float*)d_in[0];
    const int*   ei   = (const int*)d_in[1];
    const float* W1   = (const float*)d_in[2];
    const float* as1w = (const float*)d_in[3];
    const float* ad1w = (const float*)d_in[4];
    const float* b1   = (const float*)d_in[5];
    const float* W2   = (const float*)d_in[6];
    const float* as2w = (const float*)d_in[7];
    const float* ad2w = (const float*)d_in[8];
    const float* b2   = (const float*)d_in[9];
    const float* fcw  = (const float*)d_in[10];
    const float* fcb  = (const float*)d_in[11];
    float* out = (float*)d_out;

    const int* src = ei;
    const int* dst = ei + EE;

    char* base = (char*)d_ws;
    size_t off = 0;
    auto alloc = [&](size_t bytes) -> void* {
        void* p = base + off;
        off = (off + bytes + 255) & ~(size_t)255;
        return p;
    };
    int*   rowptr   = (int*)alloc((NN + 1) * sizeof(int));
    int*   cnt      = (int*)alloc(NN * sizeof(int));
    int*   tmp      = (int*)alloc(NN * sizeof(int));
    int*   bsum     = (int*)alloc(SG * sizeof(int));
    int*   boff     = (int*)alloc(SG * sizeof(int));
    int*   writeptr = (int*)alloc(NN * sizeof(int));
    int*   csr      = (int*)alloc(ET * sizeof(int));
    unsigned short* xt1 = (unsigned short*)alloc((size_t)NN * 256 * sizeof(unsigned short));
    float* h1       = (float*)alloc((size_t)NN * 256 * sizeof(float));
    float* as1      = (float*)alloc(NN * 4 * sizeof(float));
    float* ad1      = (float*)alloc(NN * 4 * sizeof(float));
    float* as2      = (float*)alloc(NN * sizeof(float));
    float* ad2      = (float*)alloc(NN * sizeof(float));
    float* Wt1      = (float*)alloc(256 * 128 * sizeof(float));
    float* Wt2      = (float*)alloc(64 * 256 * sizeof(float));
    unsigned short* xt2 = xt1;  // xt1 dead after l1_agg; reuse

    // CSR build (parallel scan)
    k_init_cnt<<<(NN + 255) / 256, 256, 0, stream>>>(cnt);
    k_hist<<<(EE + 255) / 256, 256, 0, stream>>>(dst, cnt);
    k_scan1<<<SG, 256, 0, stream>>>(cnt, tmp, bsum);
    k_scan2<<<1, 256, 0, stream>>>(bsum, boff);
    k_scan3_prep<<<SG, 256, 0, stream>>>(tmp, boff, rowptr, writeptr, csr);
    k_scatter<<<(EE + 255) / 256, 256, 0, stream>>>(src, dst, writeptr, csr);

    // weight transposes
    k_tr<<<(256 * 128 + 255) / 256, 256, 0, stream>>>(W1, Wt1, 256, 128);
    k_tr<<<(64 * 256 + 255) / 256, 256, 0, stream>>>(W2, Wt2, 64, 256);

    int gblocks = (NN + 63) / 64;  // 782
    k_gemm_att<128, 256, 4><<<gblocks, 256, 0, stream>>>(x, Wt1, as1w, ad1w, xt1, as1, ad1, NN);
    k_l1_agg<<<NN, 256, 0, stream>>>(xt1, as1, ad1, rowptr, csr, b1, h1);
    k_gemm_att<256, 64, 1><<<gblocks, 256, 0, stream>>>(h1, Wt2, as2w, ad2w, xt2, as2, ad2, NN);
    k_l2_agg<<<NN, 256, 0, stream>>>(xt2, as2, ad2, rowptr, csr, b2, fcw, fcb, out);
}

// Round 4
// 385.688 us; speedup vs baseline: 3.7220x; 1.2095x over previous
//
#include <hip/hip_runtime.h>
#include <hip/hip_bf16.h>

#define NN 50000
#define EE 800000
#define ET (NN + EE)   // edges incl. self-loops = 850000
#define SG ((NN + 255) / 256)   // scan blocks = 196

__device__ __forceinline__ float bf2f(unsigned short u) {
    union { unsigned int i; float f; } v; v.i = ((unsigned int)u) << 16; return v.f;
}
__device__ __forceinline__ unsigned short f2bf(float f) {
    __hip_bfloat16 h = __float2bfloat16(f);
    return *reinterpret_cast<unsigned short*>(&h);
}
__device__ __forceinline__ float lrelu(float e) { return e > 0.f ? e : 0.2f * e; }

// ---------------- CSR build ----------------

__global__ void k_init_cnt(int* __restrict__ cnt) {
    int i = blockIdx.x * blockDim.x + threadIdx.x;
    if (i < NN) cnt[i] = 1;   // self-loop pre-counted
}

__global__ void k_hist(const int* __restrict__ dst, int* __restrict__ cnt) {
    int i = blockIdx.x * blockDim.x + threadIdx.x;
    if (i < EE) atomicAdd(&cnt[dst[i]], 1);
}

__global__ __launch_bounds__(256) void k_scan1(const int* __restrict__ cnt,
                                               int* __restrict__ tmp, int* __restrict__ bsum) {
    int b = blockIdx.x, t = threadIdx.x, i = b * 256 + t;
    int lane = t & 63, w = t >> 6;
    int v = (i < NN) ? cnt[i] : 0;
    int s = v;
    #pragma unroll
    for (int off = 1; off < 64; off <<= 1) {
        int u = __shfl_up(s, off);
        if (lane >= off) s += u;
    }
    __shared__ int ws[4];
    if (lane == 63) ws[w] = s;
    __syncthreads();
    if (t == 0) {
        int a = 0;
        #pragma unroll
        for (int k = 0; k < 4; k++) { int x = ws[k]; ws[k] = a; a += x; }
        bsum[b] = a;
    }
    __syncthreads();
    s += ws[w];
    if (i < NN) tmp[i] = s;   // inclusive within block
}

__global__ __launch_bounds__(256) void k_scan2(const int* __restrict__ bsum, int* __restrict__ boff) {
    int t = threadIdx.x, lane = t & 63, w = t >> 6;
    int v = (t < SG) ? bsum[t] : 0;
    int s = v;
    #pragma unroll
    for (int off = 1; off < 64; off <<= 1) {
        int u = __shfl_up(s, off);
        if (lane >= off) s += u;
    }
    __shared__ int ws[4];
    if (lane == 63) ws[w] = s;
    __syncthreads();
    if (t == 0) {
        int a = 0;
        #pragma unroll
        for (int k = 0; k < 4; k++) { int x = ws[k]; ws[k] = a; a += x; }
    }
    __syncthreads();
    s += ws[w];
    if (t < SG) boff[t] = s - v;   // exclusive
}

__global__ void k_scan3_prep(const int* __restrict__ tmp, const int* __restrict__ boff,
                             int* __restrict__ rowptr, int* __restrict__ writeptr,
                             int* __restrict__ csr, int* __restrict__ dstarr) {
    int i = blockIdx.x * blockDim.x + threadIdx.x;
    if (i == 0) rowptr[0] = 0;
    if (i < NN) {
        int incl = tmp[i] + boff[i >> 8];
        rowptr[i + 1] = incl;
        int v = (i & 255) ? tmp[i - 1] + boff[i >> 8] : boff[i >> 8];  // exclusive = rowptr[i]
        csr[v] = i;            // self-loop first
        dstarr[v] = i;
        writeptr[i] = v + 1;
    }
}

__global__ void k_scatter(const int* __restrict__ src, const int* __restrict__ dst,
                          int* __restrict__ writeptr, int* __restrict__ csr,
                          int* __restrict__ dstarr) {
    int i = blockIdx.x * blockDim.x + threadIdx.x;
    if (i < EE) {
        int d = dst[i];
        int pos = atomicAdd(&writeptr[d], 1);
        csr[pos] = src[i];
        dstarr[pos] = d;
    }
}

// ---------------- weight transpose ----------------
__global__ void k_tr(const float* __restrict__ W, float* __restrict__ Wt, int Nrows, int Kcols) {
    int i = blockIdx.x * blockDim.x + threadIdx.x;
    if (i < Nrows * Kcols) {
        int n = i / Kcols, k = i % Kcols;
        Wt[k * Nrows + n] = W[i];
    }
}

// ---------------- tiled GEMM, bf16 C output, fused attention-score epilogue ----------------
template<int K, int N, int NH>
__global__ __launch_bounds__(256) void k_gemm_att(
    const float* __restrict__ A, const float* __restrict__ Wt,
    const float* __restrict__ atts, const float* __restrict__ attd,
    unsigned short* __restrict__ C, float* __restrict__ as_, float* __restrict__ ad_,
    int M)
{
    constexpr int QJ = N / 64;
    constexpr int KT = 32;
    __shared__ float xs[64][KT + 1];
    __shared__ float ws[KT][N];
    int t = threadIdx.x;
    int tx = t & 15, ty = t >> 4;
    int m0 = blockIdx.x * 64;

    float4 acc[4][QJ];
    #pragma unroll
    for (int i = 0; i < 4; i++)
        #pragma unroll
        for (int j = 0; j < QJ; j++) acc[i][j] = make_float4(0.f, 0.f, 0.f, 0.f);

    for (int k0 = 0; k0 < K; k0 += KT) {
        __syncthreads();
        #pragma unroll
        for (int i = 0; i < 2; i++) {
            int idx = t + 256 * i;
            int row = idx >> 3, q = idx & 7;
            int gr = m0 + row; if (gr >= M) gr = M - 1;
            float4 v = *(const float4*)(A + (size_t)gr * K + k0 + q * 4);
            *(float4*)&xs[row][q * 4] = v;
        }
        constexpr int WQ = (KT * N / 4) / 256;
        #pragma unroll
        for (int i = 0; i < WQ; i++) {
            int idx = t + 256 * i;
            int kk = idx / (N / 4), c4 = idx % (N / 4);
            float4 v = *(const float4*)(Wt + (size_t)(k0 + kk) * N + c4 * 4);
            *(float4*)&ws[kk][c4 * 4] = v;
        }
        __syncthreads();
        #pragma unroll
        for (int kk = 0; kk < KT; kk++) {
            float xv[4];
            #pragma unroll
            for (int i = 0; i < 4; i++) xv[i] = xs[ty * 4 + i][kk];
            #pragma unroll
            for (int j = 0; j < QJ; j++) {
                float4 wv = *(const float4*)&ws[kk][tx * 4 + 64 * j];
                #pragma unroll
                for (int i = 0; i < 4; i++) {
                    acc[i][j].x += xv[i] * wv.x;
                    acc[i][j].y += xv[i] * wv.y;
                    acc[i][j].z += xv[i] * wv.z;
                    acc[i][j].w += xv[i] * wv.w;
                }
            }
        }
    }

    float4 a_s[QJ], a_d[QJ];
    #pragma unroll
    for (int j = 0; j < QJ; j++) {
        a_s[j] = *(const float4*)(atts + j * 64 + tx * 4);
        a_d[j] = *(const float4*)(attd + j * 64 + tx * 4);
    }
    #pragma unroll
    for (int i = 0; i < 4; i++) {
        int row = m0 + ty * 4 + i;
        bool ok = row < M;
        float ps[QJ], pd[QJ];
        #pragma unroll
        for (int j = 0; j < QJ; j++) {
            if (ok) {
                ushort4 pk;
                pk.x = f2bf(acc[i][j].x); pk.y = f2bf(acc[i][j].y);
                pk.z = f2bf(acc[i][j].z); pk.w = f2bf(acc[i][j].w);
                *(ushort4*)(C + (size_t)row * N + tx * 4 + 64 * j) = pk;
            }
            ps[j] = acc[i][j].x * a_s[j].x + acc[i][j].y * a_s[j].y
                  + acc[i][j].z * a_s[j].z + acc[i][j].w * a_s[j].w;
            pd[j] = acc[i][j].x * a_d[j].x + acc[i][j].y * a_d[j].y
                  + acc[i][j].z * a_d[j].z + acc[i][j].w * a_d[j].w;
        }
        #pragma unroll
        for (int off = 8; off; off >>= 1) {
            #pragma unroll
            for (int j = 0; j < QJ; j++) {
                ps[j] += __shfl_xor(ps[j], off);
                pd[j] += __shfl_xor(pd[j], off);
            }
        }
        if (tx == 0 && ok) {
            if (NH == 4) {
                *(float4*)(as_ + row * 4) = make_float4(ps[0], ps[1], ps[2], ps[3]);
                *(float4*)(ad_ + row * 4) = make_float4(pd[0], pd[1], pd[2], pd[3]);
            } else {
                as_[row] = ps[0];
                ad_[row] = pd[0];
            }
        }
    }
}

// ---------------- edge-score precompute ----------------
__global__ void k_escore1(const int* __restrict__ csr, const int* __restrict__ dstarr,
                          const float* __restrict__ as1, const float* __restrict__ ad1,
                          float* __restrict__ ew) {
    int i = blockIdx.x * blockDim.x + threadIdx.x;
    if (i < ET) {
        int s = csr[i], n = dstarr[i];
        float4 a = *(const float4*)(as1 + (size_t)s * 4);
        float4 d = *(const float4*)(ad1 + (size_t)n * 4);
        float4 e;
        e.x = __expf(lrelu(a.x + d.x));
        e.y = __expf(lrelu(a.y + d.y));
        e.z = __expf(lrelu(a.z + d.z));
        e.w = __expf(lrelu(a.w + d.w));
        *(float4*)(ew + (size_t)i * 4) = e;
    }
}

__global__ void k_escore2(const int* __restrict__ csr, const int* __restrict__ dstarr,
                          const float* __restrict__ as2, const float* __restrict__ ad2,
                          float* __restrict__ ew) {
    int i = blockIdx.x * blockDim.x + threadIdx.x;
    if (i < ET) {
        int s = csr[i], n = dstarr[i];
        ew[i] = __expf(lrelu(as2[s] + ad2[n]));
    }
}

// ---------------- Layer-1 aggregation: wave-per-node, 4-deep gather pipeline ----------------
__global__ __launch_bounds__(256) void k_l1_agg(
    const unsigned short* __restrict__ xt1, const float* __restrict__ ew,
    const int* __restrict__ rowptr, const int* __restrict__ csr,
    const float* __restrict__ b1, float* __restrict__ h1)
{
    int t = threadIdx.x;
    int lane = t & 63, w = t >> 6;
    int n = blockIdx.x * 4 + w;
    int beg = rowptr[n], deg = rowptr[n + 1] - beg;
    int h = lane >> 4;

    float4 acc = make_float4(0.f, 0.f, 0.f, 0.f);
    float esum = 0.f;
    int j = 0;
    for (; j + 4 <= deg; j += 4) {
        int p = beg + j;
        int s0 = csr[p], s1 = csr[p + 1], s2 = csr[p + 2], s3 = csr[p + 3];
        float e0 = ew[(size_t)p * 4 + h];
        float e1 = ew[(size_t)(p + 1) * 4 + h];
        float e2 = ew[(size_t)(p + 2) * 4 + h];
        float e3 = ew[(size_t)(p + 3) * 4 + h];
        ushort4 r0 = *(const ushort4*)(xt1 + (size_t)s0 * 256 + 4 * lane);
        ushort4 r1 = *(const ushort4*)(xt1 + (size_t)s1 * 256 + 4 * lane);
        ushort4 r2 = *(const ushort4*)(xt1 + (size_t)s2 * 256 + 4 * lane);
        ushort4 r3 = *(const ushort4*)(xt1 + (size_t)s3 * 256 + 4 * lane);
        esum += (e0 + e1) + (e2 + e3);
        acc.x += bf2f(r0.x) * e0 + bf2f(r1.x) * e1 + bf2f(r2.x) * e2 + bf2f(r3.x) * e3;
        acc.y += bf2f(r0.y) * e0 + bf2f(r1.y) * e1 + bf2f(r2.y) * e2 + bf2f(r3.y) * e3;
        acc.z += bf2f(r0.z) * e0 + bf2f(r1.z) * e1 + bf2f(r2.z) * e2 + bf2f(r3.z) * e3;
        acc.w += bf2f(r0.w) * e0 + bf2f(r1.w) * e1 + bf2f(r2.w) * e2 + bf2f(r3.w) * e3;
    }
    for (; j < deg; j++) {
        int p = beg + j;
        int s = csr[p];
        float e = ew[(size_t)p * 4 + h];
        ushort4 r = *(const ushort4*)(xt1 + (size_t)s * 256 + 4 * lane);
        esum += e;
        acc.x += bf2f(r.x) * e; acc.y += bf2f(r.y) * e;
        acc.z += bf2f(r.z) * e; acc.w += bf2f(r.w) * e;
    }
    float rs = 1.f / (esum + 1e-16f);
    float4 b = *(const float4*)(b1 + 4 * lane);
    float4 o;
    o.x = fmaxf(acc.x * rs + b.x, 0.f);
    o.y = fmaxf(acc.y * rs + b.y, 0.f);
    o.z = fmaxf(acc.z * rs + b.z, 0.f);
    o.w = fmaxf(acc.w * rs + b.w, 0.f);
    *(float4*)(h1 + (size_t)n * 256 + 4 * lane) = o;
}

// ---------------- Layer-2 aggregation + fc + sigmoid: wave-per-node ----------------
__global__ __launch_bounds__(256) void k_l2_agg(
    const unsigned short* __restrict__ xt2, const float* __restrict__ ew,
    const int* __restrict__ rowptr, const int* __restrict__ csr,
    const float* __restrict__ b2, const float* __restrict__ fcw, const float* __restrict__ fcb,
    float* __restrict__ out)
{
    int t = threadIdx.x;
    int lane = t & 63, w = t >> 6;
    int n = blockIdx.x * 4 + w;
    int beg = rowptr[n], deg = rowptr[n + 1] - beg;

    float acc = 0.f, esum = 0.f;
    int j = 0;
    for (; j + 4 <= deg; j += 4) {
        int p = beg + j;
        int s0 = csr[p], s1 = csr[p + 1], s2 = csr[p + 2], s3 = csr[p + 3];
        float e0 = ew[p], e1 = ew[p + 1], e2 = ew[p + 2], e3 = ew[p + 3];
        float r0 = bf2f(xt2[(size_t)s0 * 64 + lane]);
        float r1 = bf2f(xt2[(size_t)s1 * 64 + lane]);
        float r2 = bf2f(xt2[(size_t)s2 * 64 + lane]);
        float r3 = bf2f(xt2[(size_t)s3 * 64 + lane]);
        esum += (e0 + e1) + (e2 + e3);
        acc += r0 * e0 + r1 * e1 + r2 * e2 + r3 * e3;
    }
    for (; j < deg; j++) {
        int p = beg + j;
        int s = csr[p];
        float e = ew[p];
        acc += bf2f(xt2[(size_t)s * 64 + lane]) * e;
        esum += e;
    }
    float o = acc / (esum + 1e-16f) + b2[lane];
    o = fmaxf(o, 0.f);
    float z = o * fcw[lane];
    #pragma unroll
    for (int off = 32; off; off >>= 1) z += __shfl_xor(z, off);
    if (lane == 0) out[n] = 1.f / (1.f + __expf(-(z + fcb[0])));
}

// ---------------- launch ----------------

extern "C" void kernel_launch(void* const* d_in, const int* in_sizes, int n_in,
                              void* d_out, int out_size, void* d_ws, size_t ws_size,
                              hipStream_t stream) {
    const float* x    = (const float*)d_in[0];
    const int*   ei   = (const int*)d_in[1];
    const float* W1   = (const float*)d_in[2];
    const float* as1w = (const float*)d_in[3];
    const float* ad1w = (const float*)d_in[4];
    const float* b1   = (const float*)d_in[5];
    const float* W2   = (const float*)d_in[6];
    const float* as2w = (const float*)d_in[7];
    const float* ad2w = (const float*)d_in[8];
    const float* b2   = (const float*)d_in[9];
    const float* fcw  = (const float*)d_in[10];
    const float* fcb  = (const float*)d_in[11];
    float* out = (float*)d_out;

    const int* src = ei;
    const int* dst = ei + EE;

    char* base = (char*)d_ws;
    size_t off = 0;
    auto alloc = [&](size_t bytes) -> void* {
        void* p = base + off;
        off = (off + bytes + 255) & ~(size_t)255;
        return p;
    };
    int*   rowptr   = (int*)alloc((NN + 1) * sizeof(int));
    int*   cnt      = (int*)alloc(NN * sizeof(int));
    int*   tmp      = (int*)alloc(NN * sizeof(int));
    int*   bsum     = (int*)alloc(SG * sizeof(int));
    int*   boff     = (int*)alloc(SG * sizeof(int));
    int*   writeptr = (int*)alloc(NN * sizeof(int));
    int*   csr      = (int*)alloc(ET * sizeof(int));
    int*   dstarr   = (int*)alloc(ET * sizeof(int));
    float* ew1      = (float*)alloc((size_t)ET * 4 * sizeof(float));
    unsigned short* xt1 = (unsigned short*)alloc((size_t)NN * 256 * sizeof(unsigned short));
    float* h1       = (float*)alloc((size_t)NN * 256 * sizeof(float));
    float* as1      = (float*)alloc(NN * 4 * sizeof(float));
    float* ad1      = (float*)alloc(NN * 4 * sizeof(float));
    float* as2      = (float*)alloc(NN * sizeof(float));
    float* ad2      = (float*)alloc(NN * sizeof(float));
    float* Wt1      = (float*)alloc(256 * 128 * sizeof(float));
    float* Wt2      = (float*)alloc(64 * 256 * sizeof(float));
    unsigned short* xt2 = xt1;   // xt1 dead after l1_agg; reuse
    float* ew2      = ew1;       // ew1 dead after l1_agg; reuse

    // CSR build (parallel scan)
    k_init_cnt<<<(NN + 255) / 256, 256, 0, stream>>>(cnt);
    k_hist<<<(EE + 255) / 256, 256, 0, stream>>>(dst, cnt);
    k_scan1<<<SG, 256, 0, stream>>>(cnt, tmp, bsum);
    k_scan2<<<1, 256, 0, stream>>>(bsum, boff);
    k_scan3_prep<<<SG, 256, 0, stream>>>(tmp, boff, rowptr, writeptr, csr, dstarr);
    k_scatter<<<(EE + 255) / 256, 256, 0, stream>>>(src, dst, writeptr, csr, dstarr);

    // weight transposes
    k_tr<<<(256 * 128 + 255) / 256, 256, 0, stream>>>(W1, Wt1, 256, 128);
    k_tr<<<(64 * 256 + 255) / 256, 256, 0, stream>>>(W2, Wt2, 64, 256);

    int gblocks = (NN + 63) / 64;  // 782
    k_gemm_att<128, 256, 4><<<gblocks, 256, 0, stream>>>(x, Wt1, as1w, ad1w, xt1, as1, ad1, NN);
    k_escore1<<<(ET + 255) / 256, 256, 0, stream>>>(csr, dstarr, as1, ad1, ew1);
    k_l1_agg<<<(NN + 3) / 4, 256, 0, stream>>>(xt1, ew1, rowptr, csr, b1, h1);
    k_gemm_att<256, 64, 1><<<gblocks, 256, 0, stream>>>(h1, Wt2, as2w, ad2w, xt2, as2, ad2, NN);
    k_escore2<<<(ET + 255) / 256, 256, 0, stream>>>(csr, dstarr, as2, ad2, ew2);
    k_l2_agg<<<(NN + 3) / 4, 256, 0, stream>>>(xt2, ew2, rowptr, csr, b2, fcw, fcb, out);
}

// Round 5
// 329.253 us; speedup vs baseline: 4.3600x; 1.1714x over previous
//
#include <hip/hip_runtime.h>
#include <hip/hip_bf16.h>

#define NN 50000
#define EE 800000
#define ET (NN + EE)   // edges incl. self-loops = 850000
#define SG ((NN + 255) / 256)   // scan blocks = 196

typedef __attribute__((ext_vector_type(8))) short short8;
typedef __attribute__((ext_vector_type(4))) float f32x4;

__device__ __forceinline__ float bf2f(unsigned short u) {
    union { unsigned int i; float f; } v; v.i = ((unsigned int)u) << 16; return v.f;
}
__device__ __forceinline__ unsigned short f2bf(float f) {
    __hip_bfloat16 h = __float2bfloat16(f);
    return *reinterpret_cast<unsigned short*>(&h);
}
__device__ __forceinline__ float lrelu(float e) { return e > 0.f ? e : 0.2f * e; }

// ---------------- CSR build ----------------

__global__ void k_init_cnt(int* __restrict__ cnt) {
    int i = blockIdx.x * blockDim.x + threadIdx.x;
    if (i < NN) cnt[i] = 1;   // self-loop pre-counted
}

__global__ void k_hist(const int* __restrict__ dst, int* __restrict__ cnt) {
    int i = blockIdx.x * blockDim.x + threadIdx.x;
    if (i < EE) atomicAdd(&cnt[dst[i]], 1);
}

__global__ __launch_bounds__(256) void k_scan1(const int* __restrict__ cnt,
                                               int* __restrict__ tmp, int* __restrict__ bsum) {
    int b = blockIdx.x, t = threadIdx.x, i = b * 256 + t;
    int lane = t & 63, w = t >> 6;
    int v = (i < NN) ? cnt[i] : 0;
    int s = v;
    #pragma unroll
    for (int off = 1; off < 64; off <<= 1) {
        int u = __shfl_up(s, off);
        if (lane >= off) s += u;
    }
    __shared__ int ws[4];
    if (lane == 63) ws[w] = s;
    __syncthreads();
    if (t == 0) {
        int a = 0;
        #pragma unroll
        for (int k = 0; k < 4; k++) { int x = ws[k]; ws[k] = a; a += x; }
        bsum[b] = a;
    }
    __syncthreads();
    s += ws[w];
    if (i < NN) tmp[i] = s;   // inclusive within block
}

__global__ __launch_bounds__(256) void k_scan2(const int* __restrict__ bsum, int* __restrict__ boff) {
    int t = threadIdx.x, lane = t & 63, w = t >> 6;
    int v = (t < SG) ? bsum[t] : 0;
    int s = v;
    #pragma unroll
    for (int off = 1; off < 64; off <<= 1) {
        int u = __shfl_up(s, off);
        if (lane >= off) s += u;
    }
    __shared__ int ws[4];
    if (lane == 63) ws[w] = s;
    __syncthreads();
    if (t == 0) {
        int a = 0;
        #pragma unroll
        for (int k = 0; k < 4; k++) { int x = ws[k]; ws[k] = a; a += x; }
    }
    __syncthreads();
    s += ws[w];
    if (t < SG) boff[t] = s - v;   // exclusive
}

__global__ void k_scan3_prep(const int* __restrict__ tmp, const int* __restrict__ boff,
                             int* __restrict__ rowptr, int* __restrict__ writeptr,
                             int* __restrict__ csr, int* __restrict__ dstarr) {
    int i = blockIdx.x * blockDim.x + threadIdx.x;
    if (i == 0) rowptr[0] = 0;
    if (i < NN) {
        int incl = tmp[i] + boff[i >> 8];
        rowptr[i + 1] = incl;
        int v = (i & 255) ? tmp[i - 1] + boff[i >> 8] : boff[i >> 8];  // exclusive = rowptr[i]
        csr[v] = i;            // self-loop first
        dstarr[v] = i;
        writeptr[i] = v + 1;
    }
}

__global__ void k_scatter(const int* __restrict__ src, const int* __restrict__ dst,
                          int* __restrict__ writeptr, int* __restrict__ csr,
                          int* __restrict__ dstarr) {
    int i = blockIdx.x * blockDim.x + threadIdx.x;
    if (i < EE) {
        int d = dst[i];
        int pos = atomicAdd(&writeptr[d], 1);
        csr[pos] = src[i];
        dstarr[pos] = d;
    }
}

// ---------------- MFMA bf16 GEMM with fused attention-score epilogue ----------------
// C[M][N](bf16) = A[M][K] @ W[N][K]^T  (W row-major [N][K], converted fp32->bf16 in staging)
// as_/ad_[m][NH] = per-head attention scores.
// Block: 256 threads (4 waves), M-tile 64. Wave w owns cols [w*N/4, (w+1)*N/4).
// LDS: A full-K (swizzled 16B units, u^=m&7), B staged in two K-halves.
template<int K, int N, int NH, bool A_BF16>
__global__ __launch_bounds__(256) void k_gemm_mfma(
    const void* __restrict__ Aptr, const float* __restrict__ W,
    const float* __restrict__ atts, const float* __restrict__ attd,
    unsigned short* __restrict__ C, float* __restrict__ as_, float* __restrict__ ad_,
    int M)
{
    constexpr int KU  = K / 8;        // 16B units per row
    constexpr int KUH = KU / 2;       // units per K-half
    constexpr int KC  = K / 32;       // mfma K-chunks
    constexpr int NW  = N / 4;        // cols per wave
    constexpr int NI  = NW / 16;      // 16-col tiles per wave
    constexpr int ABYTES = 64 * KU * 16;
    constexpr int BBYTES = N * KUH * 16;
    constexpr int SMEM = ABYTES + BBYTES + (NH == 1 ? 2048 : 0);
    __shared__ char smem[SMEM];
    char* Ash = smem;
    char* Bsh = smem + ABYTES;
    unsigned short* Csh = (unsigned short*)smem;          // overlay after compute
    float* scsh = (float*)(smem + ABYTES + BBYTES);       // NH==1 only

    int t = threadIdx.x;
    int lane = t & 63, w = t >> 6;
    int colL = lane & 15, quad = lane >> 4;
    int m0 = blockIdx.x * 64;

    // ---- stage A (full K) ----
    {
        constexpr int CNT = 64 * KU / 256;
        #pragma unroll
        for (int i = 0; i < CNT; i++) {
            int v = t + 256 * i;
            int m = v / KU, u = v % KU;
            int gr = m0 + m; if (gr >= M) gr = M - 1;
            short8 val;
            if (A_BF16) {
                val = *(const short8*)((const unsigned short*)Aptr + (size_t)gr * K + u * 8);
            } else {
                const float* Af = (const float*)Aptr;
                float4 lo = *(const float4*)(Af + (size_t)gr * K + u * 8);
                float4 hi = *(const float4*)(Af + (size_t)gr * K + u * 8 + 4);
                val[0] = (short)f2bf(lo.x); val[1] = (short)f2bf(lo.y);
                val[2] = (short)f2bf(lo.z); val[3] = (short)f2bf(lo.w);
                val[4] = (short)f2bf(hi.x); val[5] = (short)f2bf(hi.y);
                val[6] = (short)f2bf(hi.z); val[7] = (short)f2bf(hi.w);
            }
            *(short8*)(Ash + ((size_t)m * KU + (u ^ (m & 7))) * 16) = val;
        }
    }

    f32x4 acc[4][NI];
    #pragma unroll
    for (int mi = 0; mi < 4; mi++)
        #pragma unroll
        for (int ni = 0; ni < NI; ni++) acc[mi][ni] = (f32x4){0.f, 0.f, 0.f, 0.f};

    #pragma unroll
    for (int kh = 0; kh < 2; kh++) {
        __syncthreads();
        // ---- stage B half ----
        {
            constexpr int CNT = N * KUH / 256;
            #pragma unroll
            for (int i = 0; i < CNT; i++) {
                int v = t + 256 * i;
                int n = v / KUH, uu = v % KUH;
                int u = kh * KUH + uu;
                float4 lo = *(const float4*)(W + (size_t)n * K + u * 8);
                float4 hi = *(const float4*)(W + (size_t)n * K + u * 8 + 4);
                short8 val;
                val[0] = (short)f2bf(lo.x); val[1] = (short)f2bf(lo.y);
                val[2] = (short)f2bf(lo.z); val[3] = (short)f2bf(lo.w);
                val[4] = (short)f2bf(hi.x); val[5] = (short)f2bf(hi.y);
                val[6] = (short)f2bf(hi.z); val[7] = (short)f2bf(hi.w);
                *(short8*)(Bsh + ((size_t)n * KUH + (uu ^ (n & 7))) * 16) = val;
            }
        }
        __syncthreads();
        #pragma unroll
        for (int kcl = 0; kcl < KC / 2; kcl++) {
            int uA = (kh * (KC / 2) + kcl) * 4 + quad;
            int uB = kcl * 4 + quad;
            short8 bf[NI];
            #pragma unroll
            for (int ni = 0; ni < NI; ni++) {
                int n = w * NW + ni * 16 + colL;
                bf[ni] = *(const short8*)(Bsh + ((size_t)n * KUH + (uB ^ (n & 7))) * 16);
            }
            #pragma unroll
            for (int mi = 0; mi < 4; mi++) {
                int m = mi * 16 + colL;
                short8 af = *(const short8*)(Ash + ((size_t)m * KU + (uA ^ (m & 7))) * 16);
                #pragma unroll
                for (int ni = 0; ni < NI; ni++)
                    acc[mi][ni] = __builtin_amdgcn_mfma_f32_16x16x32_bf16(af, bf[ni], acc[mi][ni], 0, 0, 0);
            }
        }
    }
    __syncthreads();   // all LDS reads done; Csh/scsh overlay safe

    // ---- attention scores ----
    float asv[NI], adv[NI];
    #pragma unroll
    for (int ni = 0; ni < NI; ni++) {
        int na = (NH == 4) ? (w * 64 + ni * 16 + colL) : (w * 16 + colL);
        asv[ni] = atts[na];
        adv[ni] = attd[na];
    }
    #pragma unroll
    for (int mi = 0; mi < 4; mi++) {
        float ps[4] = {0.f, 0.f, 0.f, 0.f}, pd[4] = {0.f, 0.f, 0.f, 0.f};
        #pragma unroll
        for (int ni = 0; ni < NI; ni++)
            #pragma unroll
            for (int r = 0; r < 4; r++) {
                ps[r] += acc[mi][ni][r] * asv[ni];
                pd[r] += acc[mi][ni][r] * adv[ni];
            }
        #pragma unroll
        for (int off = 1; off < 16; off <<= 1)
            #pragma unroll
            for (int r = 0; r < 4; r++) {
                ps[r] += __shfl_xor(ps[r], off);
                pd[r] += __shfl_xor(pd[r], off);
            }
        if (colL == 0) {
            #pragma unroll
            for (int r = 0; r < 4; r++) {
                int rloc = mi * 16 + quad * 4 + r;
                if (NH == 4) {
                    int row = m0 + rloc;
                    if (row < M) {
                        as_[(size_t)row * 4 + w] = ps[r];
                        ad_[(size_t)row * 4 + w] = pd[r];
                    }
                } else {
                    scsh[(w * 64 + rloc) * 2 + 0] = ps[r];
                    scsh[(w * 64 + rloc) * 2 + 1] = pd[r];
                }
            }
        }
    }

    // ---- C repack to LDS (bf16) ----
    #pragma unroll
    for (int mi = 0; mi < 4; mi++)
        #pragma unroll
        for (int ni = 0; ni < NI; ni++)
            #pragma unroll
            for (int r = 0; r < 4; r++)
                Csh[(size_t)(mi * 16 + quad * 4 + r) * (N + 8) + w * NW + ni * 16 + colL] =
                    f2bf(acc[mi][ni][r]);
    __syncthreads();

    // ---- coalesced global store ----
    {
        constexpr int CNT = 64 * (N / 8) / 256;
        #pragma unroll
        for (int i = 0; i < CNT; i++) {
            int v = t + 256 * i;
            int m = v / (N / 8), u = v % (N / 8);
            int row = m0 + m;
            if (row < M)
                *(short8*)(C + (size_t)row * N + u * 8) =
                    *(const short8*)(Csh + (size_t)m * (N + 8) + u * 8);
        }
    }
    if (NH == 1 && t < 64) {
        int row = m0 + t;
        if (row < M) {
            float s = 0.f, d = 0.f;
            #pragma unroll
            for (int ww = 0; ww < 4; ww++) {
                s += scsh[(ww * 64 + t) * 2 + 0];
                d += scsh[(ww * 64 + t) * 2 + 1];
            }
            as_[row] = s;
            ad_[row] = d;
        }
    }
}

// ---------------- edge-score precompute ----------------
__global__ void k_escore1(const int* __restrict__ csr, const int* __restrict__ dstarr,
                          const float* __restrict__ as1, const float* __restrict__ ad1,
                          float* __restrict__ ew) {
    int i = blockIdx.x * blockDim.x + threadIdx.x;
    if (i < ET) {
        int s = csr[i], n = dstarr[i];
        float4 a = *(const float4*)(as1 + (size_t)s * 4);
        float4 d = *(const float4*)(ad1 + (size_t)n * 4);
        float4 e;
        e.x = __expf(lrelu(a.x + d.x));
        e.y = __expf(lrelu(a.y + d.y));
        e.z = __expf(lrelu(a.z + d.z));
        e.w = __expf(lrelu(a.w + d.w));
        *(float4*)(ew + (size_t)i * 4) = e;
    }
}

__global__ void k_escore2(const int* __restrict__ csr, const int* __restrict__ dstarr,
                          const float* __restrict__ as2, const float* __restrict__ ad2,
                          float* __restrict__ ew) {
    int i = blockIdx.x * blockDim.x + threadIdx.x;
    if (i < ET) {
        int s = csr[i], n = dstarr[i];
        ew[i] = __expf(lrelu(as2[s] + ad2[n]));
    }
}

// ---------------- Layer-1 aggregation: wave/node, half-wave/edge, ushort8 gathers ----------------
__global__ __launch_bounds__(256) void k_l1_agg(
    const unsigned short* __restrict__ xt1, const float* __restrict__ ew,
    const int* __restrict__ rowptr, const int* __restrict__ csr,
    const float* __restrict__ b1, unsigned short* __restrict__ h1)
{
    int t = threadIdx.x;
    int lane = t & 63, w = t >> 6;
    int n = blockIdx.x * 4 + w;
    int beg = rowptr[n], deg = rowptr[n + 1] - beg;
    int half = lane >> 5, c = lane & 31, h = c >> 3;  // lane owns channels 8c..8c+7

    float acc[8] = {0.f, 0.f, 0.f, 0.f, 0.f, 0.f, 0.f, 0.f};
    float esum = 0.f;
    int j = 0;
    for (; j + 4 <= deg; j += 4) {
        int p = beg + j + half * 2;
        int s0 = csr[p], s1 = csr[p + 1];
        float e0 = ew[(size_t)p * 4 + h];
        float e1 = ew[(size_t)(p + 1) * 4 + h];
        short8 r0 = *(const short8*)(xt1 + (size_t)s0 * 256 + c * 8);
        short8 r1 = *(const short8*)(xt1 + (size_t)s1 * 256 + c * 8);
        esum += e0 + e1;
        #pragma unroll
        for (int k = 0; k < 8; k++)
            acc[k] += bf2f((unsigned short)r0[k]) * e0 + bf2f((unsigned short)r1[k]) * e1;
    }
    for (; j < deg; j += 2) {
        int jj = j + half;
        if (jj < deg) {
            int p = beg + jj;
            int s = csr[p];
            float e = ew[(size_t)p * 4 + h];
            short8 r = *(const short8*)(xt1 + (size_t)s * 256 + c * 8);
            esum += e;
            #pragma unroll
            for (int k = 0; k < 8; k++) acc[k] += bf2f((unsigned short)r[k]) * e;
        }
    }
    #pragma unroll
    for (int k = 0; k < 8; k++) acc[k] += __shfl_xor(acc[k], 32);
    esum += __shfl_xor(esum, 32);
    if (half == 0) {
        float rs = 1.f / (esum + 1e-16f);
        float4 bl = *(const float4*)(b1 + c * 8);
        float4 bh = *(const float4*)(b1 + c * 8 + 4);
        float bb[8] = {bl.x, bl.y, bl.z, bl.w, bh.x, bh.y, bh.z, bh.w};
        short8 o;
        #pragma unroll
        for (int k = 0; k < 8; k++)
            o[k] = (short)f2bf(fmaxf(acc[k] * rs + bb[k], 0.f));
        *(short8*)(h1 + (size_t)n * 256 + c * 8) = o;
    }
}

// ---------------- Layer-2 aggregation + fc + sigmoid: wave/node, half-wave/edge ----------------
__global__ __launch_bounds__(256) void k_l2_agg(
    const unsigned short* __restrict__ xt2, const float* __restrict__ ew,
    const int* __restrict__ rowptr, const int* __restrict__ csr,
    const float* __restrict__ b2, const float* __restrict__ fcw, const float* __restrict__ fcb,
    float* __restrict__ out)
{
    int t = threadIdx.x;
    int lane = t & 63, w = t >> 6;
    int n = blockIdx.x * 4 + w;
    int beg = rowptr[n], deg = rowptr[n + 1] - beg;
    int half = lane >> 5, c = lane & 31;   // lane owns channels 2c, 2c+1

    float a0 = 0.f, a1 = 0.f, esum = 0.f;
    int j = 0;
    for (; j + 4 <= deg; j += 4) {
        int p = beg + j + half * 2;
        int s0 = csr[p], s1 = csr[p + 1];
        float e0 = ew[p], e1 = ew[p + 1];
        unsigned int r0 = *(const unsigned int*)(xt2 + (size_t)s0 * 64 + c * 2);
        unsigned int r1 = *(const unsigned int*)(xt2 + (size_t)s1 * 64 + c * 2);
        esum += e0 + e1;
        a0 += bf2f(r0 & 0xffff) * e0 + bf2f(r1 & 0xffff) * e1;
        a1 += bf2f(r0 >> 16) * e0 + bf2f(r1 >> 16) * e1;
    }
    for (; j < deg; j += 2) {
        int jj = j + half;
        if (jj < deg) {
            int p = beg + jj;
            int s = csr[p];
            float e = ew[p];
            unsigned int r = *(const unsigned int*)(xt2 + (size_t)s * 64 + c * 2);
            esum += e;
            a0 += bf2f(r & 0xffff) * e;
            a1 += bf2f(r >> 16) * e;
        }
    }
    a0 += __shfl_xor(a0, 32);
    a1 += __shfl_xor(a1, 32);
    esum += __shfl_xor(esum, 32);
    if (half == 0) {
        float rs = 1.f / (esum + 1e-16f);
        float o0 = fmaxf(a0 * rs + b2[c * 2], 0.f);
        float o1 = fmaxf(a1 * rs + b2[c * 2 + 1], 0.f);
        float z = o0 * fcw[c * 2] + o1 * fcw[c * 2 + 1];
        #pragma unroll
        for (int off = 16; off; off >>= 1) z += __shfl_xor(z, off);
        if (c == 0) out[n] = 1.f / (1.f + __expf(-(z + fcb[0])));
    }
}

// ---------------- launch ----------------

extern "C" void kernel_launch(void* const* d_in, const int* in_sizes, int n_in,
                              void* d_out, int out_size, void* d_ws, size_t ws_size,
                              hipStream_t stream) {
    const float* x    = (const float*)d_in[0];
    const int*   ei   = (const int*)d_in[1];
    const float* W1   = (const float*)d_in[2];
    const float* as1w = (const float*)d_in[3];
    const float* ad1w = (const float*)d_in[4];
    const float* b1   = (const float*)d_in[5];
    const float* W2   = (const float*)d_in[6];
    const float* as2w = (const float*)d_in[7];
    const float* ad2w = (const float*)d_in[8];
    const float* b2   = (const float*)d_in[9];
    const float* fcw  = (const float*)d_in[10];
    const float* fcb  = (const float*)d_in[11];
    float* out = (float*)d_out;

    const int* src = ei;
    const int* dst = ei + EE;

    char* base = (char*)d_ws;
    size_t off = 0;
    auto alloc = [&](size_t bytes) -> void* {
        void* p = base + off;
        off = (off + bytes + 255) & ~(size_t)255;
        return p;
    };
    int*   rowptr   = (int*)alloc((NN + 1) * sizeof(int));
    int*   cnt      = (int*)alloc(NN * sizeof(int));
    int*   tmp      = (int*)alloc(NN * sizeof(int));
    int*   bsum     = (int*)alloc(SG * sizeof(int));
    int*   boff     = (int*)alloc(SG * sizeof(int));
    int*   writeptr = (int*)alloc(NN * sizeof(int));
    int*   csr      = (int*)alloc(ET * sizeof(int));
    int*   dstarr   = (int*)alloc(ET * sizeof(int));
    float* ew1      = (float*)alloc((size_t)ET * 4 * sizeof(float));
    unsigned short* xt1 = (unsigned short*)alloc((size_t)NN * 256 * sizeof(unsigned short));
    unsigned short* h1  = (unsigned short*)alloc((size_t)NN * 256 * sizeof(unsigned short));
    float* as1      = (float*)alloc(NN * 4 * sizeof(float));
    float* ad1      = (float*)alloc(NN * 4 * sizeof(float));
    float* as2      = (float*)alloc(NN * sizeof(float));
    float* ad2      = (float*)alloc(NN * sizeof(float));
    unsigned short* xt2 = xt1;   // xt1 dead after l1_agg; reuse
    float* ew2      = ew1;       // ew1 dead after l1_agg; reuse

    // CSR build (parallel scan)
    k_init_cnt<<<(NN + 255) / 256, 256, 0, stream>>>(cnt);
    k_hist<<<(EE + 255) / 256, 256, 0, stream>>>(dst, cnt);
    k_scan1<<<SG, 256, 0, stream>>>(cnt, tmp, bsum);
    k_scan2<<<1, 256, 0, stream>>>(bsum, boff);
    k_scan3_prep<<<SG, 256, 0, stream>>>(tmp, boff, rowptr, writeptr, csr, dstarr);
    k_scatter<<<(EE + 255) / 256, 256, 0, stream>>>(src, dst, writeptr, csr, dstarr);

    int gblocks = (NN + 63) / 64;  // 782
    k_gemm_mfma<128, 256, 4, false><<<gblocks, 256, 0, stream>>>(
        x, W1, as1w, ad1w, xt1, as1, ad1, NN);
    k_escore1<<<(ET + 255) / 256, 256, 0, stream>>>(csr, dstarr, as1, ad1, ew1);
    k_l1_agg<<<(NN + 3) / 4, 256, 0, stream>>>(xt1, ew1, rowptr, csr, b1, h1);
    k_gemm_mfma<256, 64, 1, true><<<gblocks, 256, 0, stream>>>(
        h1, W2, as2w, ad2w, xt2, as2, ad2, NN);
    k_escore2<<<(ET + 255) / 256, 256, 0, stream>>>(csr, dstarr, as2, ad2, ew2);
    k_l2_agg<<<(NN + 3) / 4, 256, 0, stream>>>(xt2, ew2, rowptr, csr, b2, fcw, fcb, out);
}